// Round 6
// baseline (177.843 us; speedup 1.0000x reference)
//
#include <hip/hip_runtime.h>
#include <hip/hip_bf16.h>

#define TB 64     // batches
#define SL 512    // MAX_LEN (all sequences full length)
#define DIM 1024  // feature dim
#define LAT 512   // latent dim

// Tiled bf16 row-block stride in ELEMENTS (16 rows x 1024 cols = 16384 + 256 pad).
#define RBS 16640

typedef short short8 __attribute__((ext_vector_type(8)));
typedef unsigned uint4v __attribute__((ext_vector_type(4)));
typedef float f32x4 __attribute__((ext_vector_type(4)));

__device__ inline unsigned bfr(float f) {   // fp32 -> bf16 bits (RNE), low 16
    unsigned u = __builtin_bit_cast(unsigned, f);
    u += 0x7FFFu + ((u >> 16) & 1u);
    return u >> 16;
}
__device__ inline unsigned pk2(float lo, float hi) {   // pack 2 bf16 into u32
    return bfr(lo) | (bfr(hi) << 16);
}

// ============================================================================
// Tiled bf16 layout: T[rb][cb][16][32], rb = row/16 (2048), cb = col/32 (32).
// One 16x32 tile (1KB) == one MFMA A/B fragment: lane l reads 16B at
// (l&15)*64 + (l>>4)*16  -> a single fully-coalesced 1KB wave load.
// addr(elems) = rb*RBS + cb*512 + r*32 + c
// ============================================================================

// K0: fp32 row-major -> bf16 tiled. Block g handles rows g*16..g*16+15.
__global__ __launch_bounds__(256) void k0_convert(const float* __restrict__ seq,
                                                  unsigned short* __restrict__ tb) {
    const int gblk = blockIdx.x;          // 2048 row-groups
    const int tid = threadIdx.x;
    const float* src = seq + (size_t)gblk * 16 * DIM;
    unsigned short* dst = tb + (size_t)gblk * RBS;
    const int cb = tid >> 3;              // tile column 0..31
    const int cc = (tid & 7) * 4;         // col within tile
#pragma unroll
    for (int j = 0; j < 16; ++j) {
        float4 v = *(const float4*)(src + (size_t)j * DIM + tid * 4);
        unsigned short* d = dst + cb * 512 + j * 32 + cc;
        uint2 w;
        w.x = pk2(v.x, v.y);
        w.y = pk2(v.z, v.w);
        *(uint2*)d = w;
    }
}

// K1 v3: per-(batch, 64-q-row tile) block, 512 threads (8 waves).
// Wave w owns k columns {nb*128 + w*16}; all 64 q rows (mt=0..3).
// Register-double-buffered fragment loads: while MFMAs consume buffer A,
// buffer B's 8 x 1KB loads are in flight (1-deep software pipeline).
__global__ __launch_bounds__(512, 4) void k1_scores(const unsigned short* __restrict__ tb,
                                                    float* __restrict__ c_part) {
    const int blk = blockIdx.x;            // 512 = 8 q-tiles * 64 batches
    const int b = blk & 63, qt = blk >> 6; // same-batch tiles co-XCD
    const int tid = threadIdx.x;
    const int w = tid >> 6, lane = tid & 63;
    const int g = lane >> 4, l15 = lane & 15;

    __shared__ float lred[64][8];
    __shared__ float invl[64];

    const int laneoff = l15 * 32 + g * 8;  // within-tile elem offset
    const unsigned short* qb = tb + (size_t)(b * 32 + qt * 4) * RBS + laneoff;
    const unsigned short* kb = tb + (size_t)(b * 32 + w) * RBS + laneoff;

    f32x4 acc[4][4];   // [nb][mt]
#pragma unroll
    for (int nb = 0; nb < 4; ++nb)
#pragma unroll
        for (int mt = 0; mt < 4; ++mt) acc[nb][mt] = (f32x4){0.f, 0.f, 0.f, 0.f};

#define LOADF(dq, dk, ds_) {                                              \
    const unsigned short* qcol = qb + (ds_) * 512;                        \
    const unsigned short* kcol = kb + (ds_) * 512;                        \
    _Pragma("unroll") for (int mt = 0; mt < 4; ++mt)                      \
        dq[mt] = *(const short8*)(qcol + (size_t)mt * RBS);               \
    _Pragma("unroll") for (int nb = 0; nb < 4; ++nb)                      \
        dk[nb] = *(const short8*)(kcol + (size_t)nb * 8 * RBS);           \
}
#define MFMAS(q_, k_) {                                                   \
    _Pragma("unroll") for (int nb = 0; nb < 4; ++nb)                      \
        _Pragma("unroll") for (int mt = 0; mt < 4; ++mt)                  \
            acc[nb][mt] = __builtin_amdgcn_mfma_f32_16x16x32_bf16(        \
                q_[mt], k_[nb], acc[nb][mt], 0, 0, 0);                    \
}

    short8 qA[4], kA[4], qB[4], kB[4];
    LOADF(qA, kA, 0);
    for (int ds = 0; ds < 32; ds += 2) {
        LOADF(qB, kB, ds + 1);      // prefetch odd stage
        MFMAS(qA, kA);              // consume even stage
        if (ds + 2 < 32) LOADF(qA, kA, ds + 2);   // prefetch next even
        MFMAS(qB, kB);              // consume odd stage
    }
#undef LOADF
#undef MFMAS

    // exp (scale = 1/sqrt(1024) = 1/32); q = mt*16 + g*4 + r, k = nb*128 + w*16 + l15
#pragma unroll
    for (int nb = 0; nb < 4; ++nb)
#pragma unroll
        for (int mt = 0; mt < 4; ++mt) {
            f32x4 t = acc[nb][mt];
#pragma unroll
            for (int r = 0; r < 4; ++r) t[r] = __expf(t[r] * 0.03125f);
            acc[nb][mt] = t;
        }

    // row sums: per-thread over nb, then over the 16-lane l15 group
    float rp[4][4];
#pragma unroll
    for (int mt = 0; mt < 4; ++mt)
#pragma unroll
        for (int r = 0; r < 4; ++r) {
            float s = 0.f;
#pragma unroll
            for (int nb = 0; nb < 4; ++nb) s += acc[nb][mt][r];
            rp[mt][r] = s;
        }
#pragma unroll
    for (int m = 1; m <= 8; m <<= 1)
#pragma unroll
        for (int mt = 0; mt < 4; ++mt)
#pragma unroll
            for (int r = 0; r < 4; ++r)
                rp[mt][r] += __shfl_xor(rp[mt][r], m, 64);
    if (l15 == 0) {
#pragma unroll
        for (int mt = 0; mt < 4; ++mt)
#pragma unroll
            for (int r = 0; r < 4; ++r)
                lred[mt * 16 + g * 4 + r][w] = rp[mt][r];
    }
    __syncthreads();
    if (tid < 64) {
        float l = 0.f;
#pragma unroll
        for (int ww = 0; ww < 8; ++ww) l += lred[tid][ww];
        invl[tid] = 1.0f / l;
    }
    __syncthreads();

    float iq[4][4];
#pragma unroll
    for (int mt = 0; mt < 4; ++mt)
#pragma unroll
        for (int r = 0; r < 4; ++r)
            iq[mt][r] = invl[mt * 16 + g * 4 + r];

    // weighted column sums over this block's 64 q rows
#pragma unroll
    for (int nb = 0; nb < 4; ++nb) {
        float cp = 0.f;
#pragma unroll
        for (int mt = 0; mt < 4; ++mt)
#pragma unroll
            for (int r = 0; r < 4; ++r) cp += acc[nb][mt][r] * iq[mt][r];
        cp += __shfl_xor(cp, 16, 64);
        cp += __shfl_xor(cp, 32, 64);
        if (lane < 16)
            c_part[(size_t)blk * 512 + nb * 128 + w * 16 + lane] = cp;
    }
}

// K2 v2: pooled_part from the bf16 tiled buffer.
__global__ __launch_bounds__(256) void k2_pool(const unsigned short* __restrict__ tb,
                                               const float* __restrict__ c_part,
                                               float* __restrict__ pooled_part) {
    const int blk = blockIdx.x;          // 256 = 64 batches * 4 key-ranges
    const int b = blk >> 2, kt = blk & 3;
    const int tid = threadIdx.x;
    __shared__ float cw[128];
    if (tid < 128) {
        int k = kt * 128 + tid;
        float s = 0.f;
#pragma unroll
        for (int qt = 0; qt < 8; ++qt) s += c_part[(size_t)(qt * 64 + b) * 512 + k];
        cw[tid] = s;
    }
    __syncthreads();
    // lane covers d = tid*4 .. tid*4+3 (one ushort4 per key row)
    const int cb = tid >> 3;              // d/32
    const int cc = (tid & 7) * 4;         // d%32
    float a0 = 0.f, a1 = 0.f, a2 = 0.f, a3 = 0.f;
    const unsigned short* base = tb + (size_t)(b * 32 + kt * 8) * RBS + cb * 512 + cc;
    for (int kk = 0; kk < 128; ++kk) {
        float c = cw[kk];
        const unsigned short* p = base + (size_t)(kk >> 4) * RBS + (kk & 15) * 32;
        uint2 u = *(const uint2*)p;
        a0 += c * __builtin_bit_cast(float, u.x << 16);
        a1 += c * __builtin_bit_cast(float, u.x & 0xFFFF0000u);
        a2 += c * __builtin_bit_cast(float, u.y << 16);
        a3 += c * __builtin_bit_cast(float, u.y & 0xFFFF0000u);
    }
    float* dst = pooled_part + (size_t)(b * 4 + kt) * DIM + tid * 4;
    *(float4*)dst = make_float4(a0, a1, a2, a3);
}

// K3: out = pooled @ W + bias for both heads. out: [mean(64x512), log_var(64x512)]
__global__ __launch_bounds__(256) void k3_out(const float* __restrict__ pooled_part,
                                              const float* __restrict__ Wm,
                                              const float* __restrict__ bm,
                                              const float* __restrict__ Wv,
                                              const float* __restrict__ bv,
                                              float* __restrict__ out) {
    const int blk = blockIdx.x;          // 128 = 64 batches * 2 heads
    const int b = blk >> 1, which = blk & 1;
    const int tid = threadIdx.x;
    const float* W = which ? Wv : Wm;
    const float* bias = which ? bv : bm;
    __shared__ float p[1024];
#pragma unroll
    for (int i = 0; i < 4; ++i) {
        int d = tid + (i << 8);
        float s = 0.f;
#pragma unroll
        for (int kt = 0; kt < 4; ++kt) s += pooled_part[(size_t)(b * 4 + kt) * DIM + d];
        p[d] = s;
    }
    __syncthreads();
    float acc0 = bias[tid], acc1 = bias[tid + 256];
    for (int d = 0; d < 1024; ++d) {
        float pv = p[d];
        const float* wr = W + (size_t)d * LAT;
        acc0 += pv * wr[tid];
        acc1 += pv * wr[tid + 256];
    }
    float* o = out + (size_t)which * TB * LAT + (size_t)b * LAT;
    o[tid] = acc0;
    o[tid + 256] = acc1;
}

// ============================ fallback path (round-3) =======================
__device__ inline short8 ldfrag_f(const char* lds, int row, int kk, int g) {
    int byte = (row * 256 + kk * 64 + (g << 4)) ^ ((row & 7) << 4);
    return *(const short8*)(lds + byte);
}
__device__ inline void stage_load_f(const float* src, float4* gg) {
    gg[0] = *(const float4*)(src);
    gg[1] = *(const float4*)(src + 4);
    gg[2] = *(const float4*)(src + 8);
    gg[3] = *(const float4*)(src + 12);
}
__device__ inline void stage_write_f(char* lds, int t, const float4* gg) {
    int r = t >> 3;
    int x0 = (t & 7) * 32;
    int sw = (r & 7) << 4;
    uint4v w0, w1;
    w0[0] = pk2(gg[0].x, gg[0].y); w0[1] = pk2(gg[0].z, gg[0].w);
    w0[2] = pk2(gg[1].x, gg[1].y); w0[3] = pk2(gg[1].z, gg[1].w);
    w1[0] = pk2(gg[2].x, gg[2].y); w1[1] = pk2(gg[2].z, gg[2].w);
    w1[2] = pk2(gg[3].x, gg[3].y); w1[3] = pk2(gg[3].z, gg[3].w);
    *(uint4v*)(lds + ((r * 256 + x0) ^ sw))      = w0;
    *(uint4v*)(lds + ((r * 256 + x0 + 16) ^ sw)) = w1;
}
__global__ __launch_bounds__(512, 2) void k1_scores_fb(const float* __restrict__ seq,
                                                       float* __restrict__ c_part) {
    const int blk = blockIdx.x;
    const int b = blk & 63, qt = blk >> 6;
    const int tid = threadIdx.x;
    const int wave = tid >> 6, lane = tid & 63;
    const int qh = wave >> 2, kq = wave & 3;
    const int g = lane >> 4, l15 = lane & 15;
    __shared__ __align__(16) char Qb[16384];
    __shared__ __align__(16) char Kb[2][16384];
    __shared__ float lred[64][4];
    __shared__ float invl[64];
    __shared__ float cred[2][512];
    const float* qbase = seq + (size_t)(b * SL + qt * 64) * DIM;
    const float* kbase = seq + (size_t)(b * SL) * DIM;
    const int sr = tid >> 3;
    const int sx = (tid & 7) * 16;
    f32x4 acc[8][2];
#pragma unroll
    for (int nb = 0; nb < 8; ++nb)
#pragma unroll
        for (int mt = 0; mt < 2; ++mt) acc[nb][mt] = (f32x4){0.f, 0.f, 0.f, 0.f};
    {
        float4 gq[4], gk[4];
        stage_load_f(qbase + (size_t)sr * DIM + sx, gq);
        stage_load_f(kbase + (size_t)sr * DIM + sx, gk);
        stage_write_f(Qb, tid, gq);
        stage_write_f(Kb[0], tid, gk);
        __syncthreads();
    }
    for (int ds = 0; ds < 8; ++ds) {
        short8 qf[2][4];
#pragma unroll
        for (int mt = 0; mt < 2; ++mt)
#pragma unroll
            for (int kk = 0; kk < 4; ++kk)
                qf[mt][kk] = ldfrag_f(Qb, qh * 32 + mt * 16 + l15, kk, g);
#pragma unroll
        for (int nb = 0; nb < 8; ++nb) {
            const char* Kc = Kb[nb & 1];
            float4 gk[4], gq[4];
            if (nb < 7) {
                stage_load_f(kbase + (size_t)((nb + 1) * 64 + sr) * DIM + ds * 128 + sx, gk);
            } else if (ds < 7) {
                stage_load_f(kbase + (size_t)sr * DIM + (ds + 1) * 128 + sx, gk);
                stage_load_f(qbase + (size_t)sr * DIM + (ds + 1) * 128 + sx, gq);
            }
            short8 bf[4];
#pragma unroll
            for (int kk = 0; kk < 4; ++kk) bf[kk] = ldfrag_f(Kc, kq * 16 + l15, kk, g);
#pragma unroll
            for (int mt = 0; mt < 2; ++mt)
#pragma unroll
                for (int kk = 0; kk < 4; ++kk)
                    acc[nb][mt] = __builtin_amdgcn_mfma_f32_16x16x32_bf16(
                        qf[mt][kk], bf[kk], acc[nb][mt], 0, 0, 0);
            __syncthreads();
            if (nb < 7) {
                stage_write_f(Kb[(nb + 1) & 1], tid, gk);
            } else if (ds < 7) {
                stage_write_f(Kb[0], tid, gk);
                stage_write_f(Qb, tid, gq);
            }
            __syncthreads();
        }
    }
#pragma unroll
    for (int nb = 0; nb < 8; ++nb)
#pragma unroll
        for (int mt = 0; mt < 2; ++mt) {
            f32x4 t = acc[nb][mt];
#pragma unroll
            for (int r = 0; r < 4; ++r) t[r] = __expf(t[r] * 0.03125f);
            acc[nb][mt] = t;
        }
    float rp[2][4];
#pragma unroll
    for (int mt = 0; mt < 2; ++mt)
#pragma unroll
        for (int r = 0; r < 4; ++r) {
            float s = 0.f;
#pragma unroll
            for (int nb = 0; nb < 8; ++nb) s += acc[nb][mt][r];
            rp[mt][r] = s;
        }
#pragma unroll
    for (int m = 1; m <= 8; m <<= 1)
#pragma unroll
        for (int mt = 0; mt < 2; ++mt)
#pragma unroll
            for (int r = 0; r < 4; ++r)
                rp[mt][r] += __shfl_xor(rp[mt][r], m, 64);
    if (l15 == 0) {
#pragma unroll
        for (int mt = 0; mt < 2; ++mt)
#pragma unroll
            for (int r = 0; r < 4; ++r)
                lred[qh * 32 + mt * 16 + g * 4 + r][kq] = rp[mt][r];
    }
    __syncthreads();
    if (tid < 64) {
        float l = lred[tid][0] + lred[tid][1] + lred[tid][2] + lred[tid][3];
        invl[tid] = 1.0f / l;
    }
    __syncthreads();
    float iq[2][4];
#pragma unroll
    for (int mt = 0; mt < 2; ++mt)
#pragma unroll
        for (int r = 0; r < 4; ++r)
            iq[mt][r] = invl[qh * 32 + mt * 16 + g * 4 + r];
#pragma unroll
    for (int nb = 0; nb < 8; ++nb) {
        float cp = 0.f;
#pragma unroll
        for (int mt = 0; mt < 2; ++mt)
#pragma unroll
            for (int r = 0; r < 4; ++r) cp += acc[nb][mt][r] * iq[mt][r];
        cp += __shfl_xor(cp, 16, 64);
        cp += __shfl_xor(cp, 32, 64);
        if (lane < 16) cred[qh][nb * 64 + kq * 16 + lane] = cp;
    }
    __syncthreads();
    c_part[(size_t)blk * 512 + tid] = cred[0][tid] + cred[1][tid];
}
__global__ __launch_bounds__(256) void k2_pool_fb(const float* __restrict__ seq,
                                                  const float* __restrict__ c_part,
                                                  float* __restrict__ pooled_part) {
    const int blk = blockIdx.x;
    const int b = blk >> 2, kt = blk & 3;
    const int tid = threadIdx.x;
    __shared__ float cw[128];
    if (tid < 128) {
        int k = kt * 128 + tid;
        float s = 0.f;
#pragma unroll
        for (int qt = 0; qt < 8; ++qt) s += c_part[(size_t)(qt * 64 + b) * 512 + k];
        cw[tid] = s;
    }
    __syncthreads();
    float a0 = 0.f, a1 = 0.f, a2 = 0.f, a3 = 0.f;
    const float* base = seq + ((size_t)b * SL + kt * 128) * DIM + tid * 4;
    for (int kk = 0; kk < 128; ++kk) {
        float c = cw[kk];
        float4 v = *(const float4*)(base + (size_t)kk * DIM);
        a0 += c * v.x; a1 += c * v.y; a2 += c * v.z; a3 += c * v.w;
    }
    float* dst = pooled_part + (size_t)(b * 4 + kt) * DIM + tid * 4;
    *(float4*)dst = make_float4(a0, a1, a2, a3);
}
// ============================================================================

extern "C" void kernel_launch(void* const* d_in, const int* in_sizes, int n_in,
                              void* d_out, int out_size, void* d_ws, size_t ws_size,
                              hipStream_t stream) {
    const float* seq = (const float*)d_in[0];
    const float* Wm  = (const float*)d_in[1];
    const float* bm  = (const float*)d_in[2];
    const float* Wv  = (const float*)d_in[3];
    const float* bv  = (const float*)d_in[4];
    float* out = (float*)d_out;

    const size_t TBELEMS = (size_t)2048 * RBS;               // padded tiled buf
    const size_t need = TBELEMS * 2 + (512 * 512 + 64 * 4 * DIM) * 4;

    if (ws_size >= need) {
        unsigned short* tbuf = (unsigned short*)d_ws;
        float* c_part      = (float*)((char*)d_ws + TBELEMS * 2);
        float* pooled_part = c_part + 512 * 512;
        hipLaunchKernelGGL(k0_convert, dim3(2048), dim3(256), 0, stream, seq, tbuf);
        hipLaunchKernelGGL(k1_scores,  dim3(512),  dim3(512), 0, stream, tbuf, c_part);
        hipLaunchKernelGGL(k2_pool,    dim3(256),  dim3(256), 0, stream, tbuf, c_part, pooled_part);
        hipLaunchKernelGGL(k3_out,     dim3(128),  dim3(256), 0, stream, pooled_part,
                           Wm, bm, Wv, bv, out);
    } else {
        float* c_part      = (float*)d_ws;
        float* pooled_part = c_part + 512 * 512;
        hipLaunchKernelGGL(k1_scores_fb, dim3(512), dim3(512), 0, stream, seq, c_part);
        hipLaunchKernelGGL(k2_pool_fb,   dim3(256), dim3(256), 0, stream, seq, c_part, pooled_part);
        hipLaunchKernelGGL(k3_out,       dim3(128), dim3(256), 0, stream, pooled_part,
                           Wm, bm, Wv, bv, out);
    }
}

// Round 7
// 132.160 us; speedup vs baseline: 1.3457x; 1.3457x over previous
//
#include <hip/hip_runtime.h>
#include <hip/hip_bf16.h>

#define TB 64     // batches
#define SL 512    // MAX_LEN (all sequences full length)
#define DIM 1024  // feature dim
#define LAT 512   // latent dim

// Tiled bf16 row-block stride in ELEMENTS (16 rows x 1024 cols = 16384 + 256 pad).
#define RBS 16640

typedef short short8 __attribute__((ext_vector_type(8)));
typedef unsigned uint4v __attribute__((ext_vector_type(4)));
typedef float f32x4 __attribute__((ext_vector_type(4)));

__device__ inline unsigned bfr(float f) {   // fp32 -> bf16 bits (RNE), low 16
    unsigned u = __builtin_bit_cast(unsigned, f);
    u += 0x7FFFu + ((u >> 16) & 1u);
    return u >> 16;
}
__device__ inline unsigned pk2(float lo, float hi) {   // pack 2 bf16 into u32
    return bfr(lo) | (bfr(hi) << 16);
}

// ============================================================================
// Tiled bf16 layout: T[rb][cb][16][32], rb = row/16 (2048), cb = col/32 (32).
// One 16x32 tile (1KB) == one MFMA A/B fragment. addr = rb*RBS + cb*512 + r*32+c
// ============================================================================

// K0: fp32 row-major -> bf16 tiled. Block g handles rows g*16..g*16+15.
__global__ __launch_bounds__(256) void k0_convert(const float* __restrict__ seq,
                                                  unsigned short* __restrict__ tb) {
    const int gblk = blockIdx.x;          // 2048 row-groups
    const int tid = threadIdx.x;
    const float* src = seq + (size_t)gblk * 16 * DIM;
    unsigned short* dst = tb + (size_t)gblk * RBS;
    const int cb = tid >> 3;              // tile column 0..31
    const int cc = (tid & 7) * 4;         // col within tile
#pragma unroll
    for (int j = 0; j < 16; ++j) {
        float4 v = *(const float4*)(src + (size_t)j * DIM + tid * 4);
        unsigned short* d = dst + cb * 512 + j * 32 + cc;
        uint2 w;
        w.x = pk2(v.x, v.y);
        w.y = pk2(v.z, v.w);
        *(uint2*)d = w;
    }
}

// Async 1KB tile copy: per-lane global src (16B granules), wave-uniform LDS dst.
#define GLDS(srcp, dstp)                                                          \
    __builtin_amdgcn_global_load_lds(                                             \
        (const __attribute__((address_space(1))) void*)(srcp),                    \
        (__attribute__((address_space(3))) void*)(dstp), 16, 0, 0)

// K1 v4: per-(batch, 64-q-row tile) block, 512 threads (8 waves).
// Wave w owns k cols {nb*128 + w*16}, q rows mt*16.. (mt=0..3).
// Double-buffered LDS staging via global_load_lds: wave w stages its own 4 K
// tiles + (if w<4) one shared Q tile for stage t+1, then computes stage t from
// LDS; one barrier per stage. Granule XOR-swizzle (x ^ (x>>3), involution)
// applied to BOTH gload source and ds_read address -> bank-uniform b128 reads.
__global__ __launch_bounds__(512, 4) void k1_scores(const unsigned short* __restrict__ tb,
                                                    float* __restrict__ c_part) {
    const int blk = blockIdx.x;            // 512 = 8 q-tiles * 64 batches
    const int b = blk & 63, qt = blk >> 6; // same-batch tiles co-XCD
    const int tid = threadIdx.x;
    const int w = tid >> 6, lane = tid & 63;
    const int g = lane >> 4, l15 = lane & 15;

    __shared__ __align__(16) unsigned short K_lds[2][32 * 512];  // 2 x 32 KB
    __shared__ __align__(16) unsigned short Q_lds[2][4 * 512];   // 2 x 4 KB
    __shared__ float lred[64][8];
    __shared__ float invl[64];

    // staging: lane's swizzled source granule (elems)
    const int gsw = (lane ^ (lane >> 3)) * 8;
    // reading: swizzled byte offset within a 1KB tile for this lane's fragment
    const int tg = l15 * 4 + g;
    const int roff = (tg ^ (tg >> 3)) * 16;

    const unsigned short* qrb = tb + (size_t)(b * 32 + qt * 4) * RBS;  // +mt*RBS
    const unsigned short* krb = tb + (size_t)(b * 32 + w) * RBS;       // +nb*8*RBS

    f32x4 acc[4][4];   // [nb][mt]
#pragma unroll
    for (int nb = 0; nb < 4; ++nb)
#pragma unroll
        for (int mt = 0; mt < 4; ++mt) acc[nb][mt] = (f32x4){0.f, 0.f, 0.f, 0.f};

#define STAGE(bufi, ds_) {                                                        \
    _Pragma("unroll") for (int nb = 0; nb < 4; ++nb)                              \
        GLDS(krb + (size_t)(nb * 8) * RBS + (ds_) * 512 + gsw,                    \
             &K_lds[bufi][(nb * 8 + w) * 512]);                                   \
    if (w < 4)                                                                    \
        GLDS(qrb + (size_t)w * RBS + (ds_) * 512 + gsw,                           \
             &Q_lds[bufi][w * 512]);                                              \
}

    STAGE(0, 0);
    __syncthreads();   // drains vmcnt(0) before barrier -> buf 0 ready

    for (int ds = 0; ds < 32; ++ds) {
        const int cur = ds & 1;
        if (ds + 1 < 32) STAGE(cur ^ 1, ds + 1);   // issue next stage early

        const char* Kc = (const char*)K_lds[cur];
        const char* Qc = (const char*)Q_lds[cur];
        short8 qf[4], kf[4];
#pragma unroll
        for (int mt = 0; mt < 4; ++mt)
            qf[mt] = *(const short8*)(Qc + mt * 1024 + roff);
#pragma unroll
        for (int nb = 0; nb < 4; ++nb)
            kf[nb] = *(const short8*)(Kc + (nb * 8 + w) * 1024 + roff);
#pragma unroll
        for (int nb = 0; nb < 4; ++nb)
#pragma unroll
            for (int mt = 0; mt < 4; ++mt)
                acc[nb][mt] = __builtin_amdgcn_mfma_f32_16x16x32_bf16(
                    qf[mt], kf[nb], acc[nb][mt], 0, 0, 0);

        __syncthreads();   // drains vmcnt (stage t+1 landed) + publishes buffer
    }
#undef STAGE

    // exp (scale 1/32); q = mt*16 + g*4 + r, k = nb*128 + w*16 + l15
#pragma unroll
    for (int nb = 0; nb < 4; ++nb)
#pragma unroll
        for (int mt = 0; mt < 4; ++mt) {
            f32x4 t = acc[nb][mt];
#pragma unroll
            for (int r = 0; r < 4; ++r) t[r] = __expf(t[r] * 0.03125f);
            acc[nb][mt] = t;
        }

    // row sums: per-thread over nb, then over the 16-lane l15 group
    float rp[4][4];
#pragma unroll
    for (int mt = 0; mt < 4; ++mt)
#pragma unroll
        for (int r = 0; r < 4; ++r) {
            float s = 0.f;
#pragma unroll
            for (int nb = 0; nb < 4; ++nb) s += acc[nb][mt][r];
            rp[mt][r] = s;
        }
#pragma unroll
    for (int m = 1; m <= 8; m <<= 1)
#pragma unroll
        for (int mt = 0; mt < 4; ++mt)
#pragma unroll
            for (int r = 0; r < 4; ++r)
                rp[mt][r] += __shfl_xor(rp[mt][r], m, 64);
    if (l15 == 0) {
#pragma unroll
        for (int mt = 0; mt < 4; ++mt)
#pragma unroll
            for (int r = 0; r < 4; ++r)
                lred[mt * 16 + g * 4 + r][w] = rp[mt][r];
    }
    __syncthreads();
    if (tid < 64) {
        float l = 0.f;
#pragma unroll
        for (int ww = 0; ww < 8; ++ww) l += lred[tid][ww];
        invl[tid] = 1.0f / l;
    }
    __syncthreads();

    float iq[4][4];
#pragma unroll
    for (int mt = 0; mt < 4; ++mt)
#pragma unroll
        for (int r = 0; r < 4; ++r)
            iq[mt][r] = invl[mt * 16 + g * 4 + r];

    // weighted column sums over this block's 64 q rows
#pragma unroll
    for (int nb = 0; nb < 4; ++nb) {
        float cp = 0.f;
#pragma unroll
        for (int mt = 0; mt < 4; ++mt)
#pragma unroll
            for (int r = 0; r < 4; ++r) cp += acc[nb][mt][r] * iq[mt][r];
        cp += __shfl_xor(cp, 16, 64);
        cp += __shfl_xor(cp, 32, 64);
        if (lane < 16)
            c_part[(size_t)blk * 512 + nb * 128 + w * 16 + lane] = cp;
    }
}

// K2: pooled_part from the bf16 tiled buffer.
__global__ __launch_bounds__(256) void k2_pool(const unsigned short* __restrict__ tb,
                                               const float* __restrict__ c_part,
                                               float* __restrict__ pooled_part) {
    const int blk = blockIdx.x;          // 256 = 64 batches * 4 key-ranges
    const int b = blk >> 2, kt = blk & 3;
    const int tid = threadIdx.x;
    __shared__ float cw[128];
    if (tid < 128) {
        int k = kt * 128 + tid;
        float s = 0.f;
#pragma unroll
        for (int qt = 0; qt < 8; ++qt) s += c_part[(size_t)(qt * 64 + b) * 512 + k];
        cw[tid] = s;
    }
    __syncthreads();
    const int cb = tid >> 3;              // d/32
    const int cc = (tid & 7) * 4;         // d%32
    float a0 = 0.f, a1 = 0.f, a2 = 0.f, a3 = 0.f;
    const unsigned short* base = tb + (size_t)(b * 32 + kt * 8) * RBS + cb * 512 + cc;
    for (int kk = 0; kk < 128; ++kk) {
        float c = cw[kk];
        const unsigned short* p = base + (size_t)(kk >> 4) * RBS + (kk & 15) * 32;
        uint2 u = *(const uint2*)p;
        a0 += c * __builtin_bit_cast(float, u.x << 16);
        a1 += c * __builtin_bit_cast(float, u.x & 0xFFFF0000u);
        a2 += c * __builtin_bit_cast(float, u.y << 16);
        a3 += c * __builtin_bit_cast(float, u.y & 0xFFFF0000u);
    }
    float* dst = pooled_part + (size_t)(b * 4 + kt) * DIM + tid * 4;
    *(float4*)dst = make_float4(a0, a1, a2, a3);
}

// K3: out = pooled @ W + bias for both heads. out: [mean(64x512), log_var(64x512)]
__global__ __launch_bounds__(256) void k3_out(const float* __restrict__ pooled_part,
                                              const float* __restrict__ Wm,
                                              const float* __restrict__ bm,
                                              const float* __restrict__ Wv,
                                              const float* __restrict__ bv,
                                              float* __restrict__ out) {
    const int blk = blockIdx.x;          // 128 = 64 batches * 2 heads
    const int b = blk >> 1, which = blk & 1;
    const int tid = threadIdx.x;
    const float* W = which ? Wv : Wm;
    const float* bias = which ? bv : bm;
    __shared__ float p[1024];
#pragma unroll
    for (int i = 0; i < 4; ++i) {
        int d = tid + (i << 8);
        float s = 0.f;
#pragma unroll
        for (int kt = 0; kt < 4; ++kt) s += pooled_part[(size_t)(b * 4 + kt) * DIM + d];
        p[d] = s;
    }
    __syncthreads();
    float acc0 = bias[tid], acc1 = bias[tid + 256];
    for (int d = 0; d < 1024; ++d) {
        float pv = p[d];
        const float* wr = W + (size_t)d * LAT;
        acc0 += pv * wr[tid];
        acc1 += pv * wr[tid + 256];
    }
    float* o = out + (size_t)which * TB * LAT + (size_t)b * LAT;
    o[tid] = acc0;
    o[tid + 256] = acc1;
}

// ============================ fallback path (round-3) =======================
__device__ inline short8 ldfrag_f(const char* lds, int row, int kk, int g) {
    int byte = (row * 256 + kk * 64 + (g << 4)) ^ ((row & 7) << 4);
    return *(const short8*)(lds + byte);
}
__device__ inline void stage_load_f(const float* src, float4* gg) {
    gg[0] = *(const float4*)(src);
    gg[1] = *(const float4*)(src + 4);
    gg[2] = *(const float4*)(src + 8);
    gg[3] = *(const float4*)(src + 12);
}
__device__ inline void stage_write_f(char* lds, int t, const float4* gg) {
    int r = t >> 3;
    int x0 = (t & 7) * 32;
    int sw = (r & 7) << 4;
    uint4v w0, w1;
    w0[0] = pk2(gg[0].x, gg[0].y); w0[1] = pk2(gg[0].z, gg[0].w);
    w0[2] = pk2(gg[1].x, gg[1].y); w0[3] = pk2(gg[1].z, gg[1].w);
    w1[0] = pk2(gg[2].x, gg[2].y); w1[1] = pk2(gg[2].z, gg[2].w);
    w1[2] = pk2(gg[3].x, gg[3].y); w1[3] = pk2(gg[3].z, gg[3].w);
    *(uint4v*)(lds + ((r * 256 + x0) ^ sw))      = w0;
    *(uint4v*)(lds + ((r * 256 + x0 + 16) ^ sw)) = w1;
}
__global__ __launch_bounds__(512, 2) void k1_scores_fb(const float* __restrict__ seq,
                                                       float* __restrict__ c_part) {
    const int blk = blockIdx.x;
    const int b = blk & 63, qt = blk >> 6;
    const int tid = threadIdx.x;
    const int wave = tid >> 6, lane = tid & 63;
    const int qh = wave >> 2, kq = wave & 3;
    const int g = lane >> 4, l15 = lane & 15;
    __shared__ __align__(16) char Qb[16384];
    __shared__ __align__(16) char Kb[2][16384];
    __shared__ float lred[64][4];
    __shared__ float invl[64];
    __shared__ float cred[2][512];
    const float* qbase = seq + (size_t)(b * SL + qt * 64) * DIM;
    const float* kbase = seq + (size_t)(b * SL) * DIM;
    const int sr = tid >> 3;
    const int sx = (tid & 7) * 16;
    f32x4 acc[8][2];
#pragma unroll
    for (int nb = 0; nb < 8; ++nb)
#pragma unroll
        for (int mt = 0; mt < 2; ++mt) acc[nb][mt] = (f32x4){0.f, 0.f, 0.f, 0.f};
    {
        float4 gq[4], gk[4];
        stage_load_f(qbase + (size_t)sr * DIM + sx, gq);
        stage_load_f(kbase + (size_t)sr * DIM + sx, gk);
        stage_write_f(Qb, tid, gq);
        stage_write_f(Kb[0], tid, gk);
        __syncthreads();
    }
    for (int ds = 0; ds < 8; ++ds) {
        short8 qf[2][4];
#pragma unroll
        for (int mt = 0; mt < 2; ++mt)
#pragma unroll
            for (int kk = 0; kk < 4; ++kk)
                qf[mt][kk] = ldfrag_f(Qb, qh * 32 + mt * 16 + l15, kk, g);
#pragma unroll
        for (int nb = 0; nb < 8; ++nb) {
            const char* Kc = Kb[nb & 1];
            float4 gk[4], gq[4];
            if (nb < 7) {
                stage_load_f(kbase + (size_t)((nb + 1) * 64 + sr) * DIM + ds * 128 + sx, gk);
            } else if (ds < 7) {
                stage_load_f(kbase + (size_t)sr * DIM + (ds + 1) * 128 + sx, gk);
                stage_load_f(qbase + (size_t)sr * DIM + (ds + 1) * 128 + sx, gq);
            }
            short8 bf[4];
#pragma unroll
            for (int kk = 0; kk < 4; ++kk) bf[kk] = ldfrag_f(Kc, kq * 16 + l15, kk, g);
#pragma unroll
            for (int mt = 0; mt < 2; ++mt)
#pragma unroll
                for (int kk = 0; kk < 4; ++kk)
                    acc[nb][mt] = __builtin_amdgcn_mfma_f32_16x16x32_bf16(
                        qf[mt][kk], bf[kk], acc[nb][mt], 0, 0, 0);
            __syncthreads();
            if (nb < 7) {
                stage_write_f(Kb[(nb + 1) & 1], tid, gk);
            } else if (ds < 7) {
                stage_write_f(Kb[0], tid, gk);
                stage_write_f(Qb, tid, gq);
            }
            __syncthreads();
        }
    }
#pragma unroll
    for (int nb = 0; nb < 8; ++nb)
#pragma unroll
        for (int mt = 0; mt < 2; ++mt) {
            f32x4 t = acc[nb][mt];
#pragma unroll
            for (int r = 0; r < 4; ++r) t[r] = __expf(t[r] * 0.03125f);
            acc[nb][mt] = t;
        }
    float rp[2][4];
#pragma unroll
    for (int mt = 0; mt < 2; ++mt)
#pragma unroll
        for (int r = 0; r < 4; ++r) {
            float s = 0.f;
#pragma unroll
            for (int nb = 0; nb < 8; ++nb) s += acc[nb][mt][r];
            rp[mt][r] = s;
        }
#pragma unroll
    for (int m = 1; m <= 8; m <<= 1)
#pragma unroll
        for (int mt = 0; mt < 2; ++mt)
#pragma unroll
            for (int r = 0; r < 4; ++r)
                rp[mt][r] += __shfl_xor(rp[mt][r], m, 64);
    if (l15 == 0) {
#pragma unroll
        for (int mt = 0; mt < 2; ++mt)
#pragma unroll
            for (int r = 0; r < 4; ++r)
                lred[qh * 32 + mt * 16 + g * 4 + r][kq] = rp[mt][r];
    }
    __syncthreads();
    if (tid < 64) {
        float l = lred[tid][0] + lred[tid][1] + lred[tid][2] + lred[tid][3];
        invl[tid] = 1.0f / l;
    }
    __syncthreads();
    float iq[2][4];
#pragma unroll
    for (int mt = 0; mt < 2; ++mt)
#pragma unroll
        for (int r = 0; r < 4; ++r)
            iq[mt][r] = invl[qh * 32 + mt * 16 + g * 4 + r];
#pragma unroll
    for (int nb = 0; nb < 8; ++nb) {
        float cp = 0.f;
#pragma unroll
        for (int mt = 0; mt < 2; ++mt)
#pragma unroll
            for (int r = 0; r < 4; ++r) cp += acc[nb][mt][r] * iq[mt][r];
        cp += __shfl_xor(cp, 16, 64);
        cp += __shfl_xor(cp, 32, 64);
        if (lane < 16) cred[qh][nb * 64 + kq * 16 + lane] = cp;
    }
    __syncthreads();
    c_part[(size_t)blk * 512 + tid] = cred[0][tid] + cred[1][tid];
}
__global__ __launch_bounds__(256) void k2_pool_fb(const float* __restrict__ seq,
                                                  const float* __restrict__ c_part,
                                                  float* __restrict__ pooled_part) {
    const int blk = blockIdx.x;
    const int b = blk >> 2, kt = blk & 3;
    const int tid = threadIdx.x;
    __shared__ float cw[128];
    if (tid < 128) {
        int k = kt * 128 + tid;
        float s = 0.f;
#pragma unroll
        for (int qt = 0; qt < 8; ++qt) s += c_part[(size_t)(qt * 64 + b) * 512 + k];
        cw[tid] = s;
    }
    __syncthreads();
    float a0 = 0.f, a1 = 0.f, a2 = 0.f, a3 = 0.f;
    const float* base = seq + ((size_t)b * SL + kt * 128) * DIM + tid * 4;
    for (int kk = 0; kk < 128; ++kk) {
        float c = cw[kk];
        float4 v = *(const float4*)(base + (size_t)kk * DIM);
        a0 += c * v.x; a1 += c * v.y; a2 += c * v.z; a3 += c * v.w;
    }
    float* dst = pooled_part + (size_t)(b * 4 + kt) * DIM + tid * 4;
    *(float4*)dst = make_float4(a0, a1, a2, a3);
}
// ============================================================================

extern "C" void kernel_launch(void* const* d_in, const int* in_sizes, int n_in,
                              void* d_out, int out_size, void* d_ws, size_t ws_size,
                              hipStream_t stream) {
    const float* seq = (const float*)d_in[0];
    const float* Wm  = (const float*)d_in[1];
    const float* bm  = (const float*)d_in[2];
    const float* Wv  = (const float*)d_in[3];
    const float* bv  = (const float*)d_in[4];
    float* out = (float*)d_out;

    const size_t TBELEMS = (size_t)2048 * RBS;               // padded tiled buf
    const size_t need = TBELEMS * 2 + (512 * 512 + 64 * 4 * DIM) * 4;

    if (ws_size >= need) {
        unsigned short* tbuf = (unsigned short*)d_ws;
        float* c_part      = (float*)((char*)d_ws + TBELEMS * 2);
        float* pooled_part = c_part + 512 * 512;
        hipLaunchKernelGGL(k0_convert, dim3(2048), dim3(256), 0, stream, seq, tbuf);
        hipLaunchKernelGGL(k1_scores,  dim3(512),  dim3(512), 0, stream, tbuf, c_part);
        hipLaunchKernelGGL(k2_pool,    dim3(256),  dim3(256), 0, stream, tbuf, c_part, pooled_part);
        hipLaunchKernelGGL(k3_out,     dim3(128),  dim3(256), 0, stream, pooled_part,
                           Wm, bm, Wv, bv, out);
    } else {
        float* c_part      = (float*)d_ws;
        float* pooled_part = c_part + 512 * 512;
        hipLaunchKernelGGL(k1_scores_fb, dim3(512), dim3(512), 0, stream, seq, c_part);
        hipLaunchKernelGGL(k2_pool_fb,   dim3(256), dim3(256), 0, stream, seq, c_part, pooled_part);
        hipLaunchKernelGGL(k3_out,       dim3(128), dim3(256), 0, stream, pooled_part,
                           Wm, bm, Wv, bv, out);
    }
}